// Round 6
// baseline (420.160 us; speedup 1.0000x reference)
//
#include <hip/hip_runtime.h>
#include <stdint.h>
#include <stddef.h>

typedef __bf16 bf16x8 __attribute__((ext_vector_type(8)));
typedef float  f32x4  __attribute__((ext_vector_type(4)));
typedef unsigned short u16;

#define NIN   784
#define NINP  896    // 784 padded to 14*64
#define NH    1024
#define NE    512
#define ND    64
#define NOUTP 1024

#define SBAR()   __builtin_amdgcn_s_barrier()
#define SCHED0() __builtin_amdgcn_sched_barrier(0)
#define LGKM0()  asm volatile("s_waitcnt lgkmcnt(0)" ::: "memory")
#define VM8()    asm volatile("s_waitcnt vmcnt(8)" ::: "memory")
#define VM6()    asm volatile("s_waitcnt vmcnt(6)" ::: "memory")
#define VM0()    asm volatile("s_waitcnt vmcnt(0)" ::: "memory")

// Tiled operand layout (A and B of gemm256):
//   element (r,c) -> block (r>>8)*(Cp>>6)+(c>>6), offset (r&255)*64 + ((((c>>3)&7)^(r&7))<<3) + (c&7)
// 64-wide rm-swizzled (qb, wd1b, emb): r*64 + (((d>>3)^(r&7))<<3) + (d&7)  == tiled at Cp=64

static __device__ __forceinline__ u16 f2bf(float f) {
  union { float f; unsigned u; } v; v.f = f;
  unsigned r = v.u + 0x7fffu + ((v.u >> 16) & 1u);
  return (u16)(r >> 16);
}
static __device__ __forceinline__ float bf2f(u16 b) {
  union { unsigned u; float f; } v; v.u = ((unsigned)b) << 16; return v.f;
}

static __device__ __forceinline__ size_t tiled_off(int r, int c, int Cp) {
  return ((size_t)(r >> 8) * (Cp >> 6) + (c >> 6)) * 16384
       + ((r & 255) << 6) + (((((c >> 3) & 7) ^ (r & 7))) << 3) + (c & 7);
}

// ---------- cast fp32 -> bf16, row-major ----------
__global__ void cast_rm4(const float* __restrict__ src, u16* __restrict__ dst,
                         int R, int C, int Cp) {
  int r = blockIdx.y;
  int c4 = (blockIdx.x * blockDim.x + threadIdx.x) * 4;
  if (c4 >= Cp) return;
  ushort4 o = {0, 0, 0, 0};
  if (r < R && c4 < C) {
    const float4 v = *(const float4*)&src[(size_t)r * C + c4];
    o.x = f2bf(v.x); o.y = f2bf(v.y); o.z = f2bf(v.z); o.w = f2bf(v.w);
  }
  *(ushort4*)&dst[(size_t)r * Cp + c4] = o;
}

// ---------- cast fp32 -> bf16 into tiled+swizzled layout ----------
__global__ void cast_tiled4(const float* __restrict__ src, u16* __restrict__ dst,
                            int R, int C, int Cp) {
  int r = blockIdx.y;
  int c4 = (blockIdx.x * blockDim.x + threadIdx.x) * 4;
  if (c4 >= Cp) return;
  ushort4 o = {0, 0, 0, 0};
  if (r < R && c4 < C) {
    const float4 v = *(const float4*)&src[(size_t)r * C + c4];
    o.x = f2bf(v.x); o.y = f2bf(v.y); o.z = f2bf(v.z); o.w = f2bf(v.w);
  }
  *(ushort4*)&dst[tiled_off(r, c4, Cp)] = o;
}

// ---------- cast fp32 [R][64] -> bf16 rm64-swizzled ----------
__global__ void cast_rm64swz(const float* __restrict__ src, u16* __restrict__ dst, int R) {
  int r = blockIdx.x;
  int d = threadIdx.x;   // 64
  if (r >= R) return;
  dst[r * 64 + (((d >> 3) ^ (r & 7)) << 3) + (d & 7)] = f2bf(src[r * 64 + d]);
}

// ---------- emb -> bf16 rm64-swizzled + per-code squared norm ----------
__global__ void emb_prep(const float* __restrict__ emb, u16* __restrict__ ebf,
                         float* __restrict__ cvec) {
  int j = blockIdx.x, l = threadIdx.x;
  float v = emb[j * ND + l];
  ebf[j * 64 + (((l >> 3) ^ (j & 7)) << 3) + (l & 7)] = f2bf(v);
  float s = v * v;
  #pragma unroll
  for (int off = 32; off > 0; off >>= 1) s += __shfl_down(s, off);
  if (l == 0) cvec[j] = s;
}

// =========================================================================
// 256x256-tile, BK=64, 8-wave, 8-phase GEMM, tiled operands.
// Epilogue: OMODE 0 = f32 row-major direct store; 1 = bf16 tiled via LDS.
// Handles NT==1 (used for the K=64 decoder-layer-1 GEMM).
// =========================================================================
__device__ __forceinline__ void stageL(const u16* __restrict__ src,
                                       u16* dstmat, int w, int lane) {
  #pragma unroll
  for (int i = 0; i < 4; ++i) {
    const u16* g = src + (size_t)((i * 512 + w * 64 + lane) << 3);
    u16* l = dstmat + (size_t)((i * 512 + w * 64) << 3);
    __builtin_amdgcn_global_load_lds((__attribute__((address_space(1))) void*)g,
                                     (__attribute__((address_space(3))) void*)l,
                                     16, 0, 0);
  }
}

template <int S>
__device__ __forceinline__ void ldAT(bf16x8 (&af)[4][2], const u16* mat,
                                     int wr, int lr, int hi) {
  #pragma unroll
  for (int m = 0; m < 4; ++m)
    #pragma unroll
    for (int e = 0; e < 2; ++e) {
      int row = wr * 128 + S * 64 + m * 16 + lr;
      int c = (e * 4 + hi) ^ (lr & 7);
      af[m][e] = *(const bf16x8*)&mat[row * 64 + c * 8];
    }
}

template <int S>
__device__ __forceinline__ void ldBT(bf16x8 (&bq)[2][2][2], const u16* mat,
                                     int wc, int lr, int hi) {
  #pragma unroll
  for (int f = 0; f < 2; ++f)
    #pragma unroll
    for (int e = 0; e < 2; ++e) {
      int row = wc * 64 + S * 32 + f * 16 + lr;
      int c = (e * 4 + hi) ^ (lr & 7);
      bq[S][f][e] = *(const bf16x8*)&mat[row * 64 + c * 8];
    }
}

template <int MS, int NS>
__device__ __forceinline__ void quadT(f32x4 (&acc)[8][4], bf16x8 (&af)[4][2],
                                      bf16x8 (&bq)[2][2][2]) {
  __builtin_amdgcn_s_setprio(1);
  #pragma unroll
  for (int m = 0; m < 4; ++m)
    #pragma unroll
    for (int f = 0; f < 2; ++f)
      #pragma unroll
      for (int e = 0; e < 2; ++e)
        acc[MS * 4 + m][NS * 2 + f] = __builtin_amdgcn_mfma_f32_16x16x32_bf16(
            af[m][e], bq[NS][f][e], acc[MS * 4 + m][NS * 2 + f], 0, 0, 0);
  __builtin_amdgcn_s_setprio(0);
}

template <int STG, int VW>
__device__ __forceinline__ void ktile(f32x4 (&acc)[8][4], bf16x8 (&af)[4][2],
                                      bf16x8 (&bq)[2][2][2],
                                      const u16* lA, const u16* lB,
                                      const u16* stA, const u16* stB,
                                      u16* sdA, u16* sdB,
                                      int w, int lane, int wr, int wc, int lr, int hi) {
  ldAT<0>(af, lA, wr, lr, hi); ldBT<0>(bq, lB, wc, lr, hi);
  SCHED0(); SBAR(); LGKM0(); SCHED0();
  quadT<0, 0>(acc, af, bq);
  SCHED0(); SBAR();
  ldBT<1>(bq, lB, wc, lr, hi);
  SCHED0(); SBAR(); LGKM0(); SCHED0();
  quadT<0, 1>(acc, af, bq);
  SCHED0(); SBAR();
  ldAT<1>(af, lA, wr, lr, hi);
  if (STG) stageL(stB, sdB, w, lane);
  SCHED0(); SBAR(); LGKM0(); SCHED0();
  quadT<1, 1>(acc, af, bq);
  SCHED0(); SBAR();
  if (STG) stageL(stA, sdA, w, lane);
  SCHED0(); SBAR();
  quadT<1, 0>(acc, af, bq);
  SCHED0();
  if (VW == 8) { VM8(); } else if (VW == 0) { VM0(); }
  SCHED0(); SBAR();
}

template <int ACT, int OMODE, bool NCHK>  // OMODE: 0 f32 rm direct, 1 bf16 tiled via LDS
__global__ __launch_bounds__(512, 2)
void gemm256(const u16* __restrict__ A, const u16* __restrict__ Bm,
             const float* __restrict__ bias, float* __restrict__ Cf,
             u16* __restrict__ Cb, int M, int N, int K, int ldc, int ntiles) {
  __shared__ __attribute__((aligned(128))) u16 lds[2][2][256 * 64];  // 128 KiB
  const int tid  = threadIdx.x;
  const int lane = tid & 63;
  const int w    = tid >> 6;
  const int wr   = w >> 2, wc = w & 3;
  const int lr   = lane & 15, hi = lane >> 4;

  int nwg = gridDim.x, cpx = nwg >> 3, b = blockIdx.x;
  int sb = (b & 7) * cpx + (b >> 3);
  int tm = sb / ntiles, tn = sb % ntiles;

  const int NT = K >> 6;
  const u16* Ap = A + (size_t)tm * NT * 16384;
  const u16* Bp = Bm + (size_t)tn * NT * 16384;

  f32x4 acc[8][4] = {};
  bf16x8 af[4][2], bq[2][2][2];

  stageL(Ap + 0 * 16384, &lds[0][0][0], w, lane);
  stageL(Bp + 0 * 16384, &lds[0][1][0], w, lane);
  if (NT > 1) {
    stageL(Ap + 1 * 16384, &lds[1][0][0], w, lane);
    stageL(Bp + 1 * 16384, &lds[1][1][0], w, lane);
    VM8();
  } else {
    VM0();
  }
  SCHED0(); SBAR();

  for (int t = 0; t < NT - 2; ++t) {
    const int bufi = t & 1;
    ktile<1, 8>(acc, af, bq, &lds[bufi][0][0], &lds[bufi][1][0],
                Ap + (size_t)(t + 2) * 16384, Bp + (size_t)(t + 2) * 16384,
                &lds[bufi][0][0], &lds[bufi][1][0], w, lane, wr, wc, lr, hi);
  }
  if (NT > 1) {
    const int bufi = (NT - 2) & 1;
    ktile<0, 0>(acc, af, bq, &lds[bufi][0][0], &lds[bufi][1][0],
                nullptr, nullptr, nullptr, nullptr, w, lane, wr, wc, lr, hi);
  }
  {
    const int bufi = (NT - 1) & 1;
    ktile<0, -1>(acc, af, bq, &lds[bufi][0][0], &lds[bufi][1][0],
                 nullptr, nullptr, nullptr, nullptr, w, lane, wr, wc, lr, hi);
  }

  const int c0 = tn * 256 + wc * 64;
  float bv[4];
  #pragma unroll
  for (int n = 0; n < 4; ++n) {
    int col = c0 + n * 16 + lr;
    bv[n] = (!NCHK || col < N) ? bias[col] : 0.f;
  }

  if (OMODE == 1) {
    // repack full 256x256 bf16 tile into LDS in consumer tiled layout, then linear copy
    // (safe without extra sync: every wave drained its ds_reads before the final SBAR)
    u16* lf = &lds[0][0][0];
    #pragma unroll
    for (int m = 0; m < 8; ++m)
      #pragma unroll
      for (int j = 0; j < 4; ++j) {
        int row = wr * 128 + m * 16 + hi * 4 + j;    // 0..255 block-local
        #pragma unroll
        for (int n = 0; n < 4; ++n) {
          int col = wc * 64 + n * 16 + lr;           // 0..255 block-local
          float v = acc[m][n][j] + bv[n];
          if (ACT == 1) v = fmaxf(v, 0.f);
          lf[(col >> 6) * 16384 + row * 64 + ((((col >> 3) & 7) ^ (row & 7)) << 3) + (col & 7)] = f2bf(v);
        }
      }
    __syncthreads();
    u16* dst = Cb + ((size_t)tm * (ldc >> 6) + tn * 4) * 16384;
    #pragma unroll
    for (int it = 0; it < 16; ++it) {
      int idx = it * 512 + tid;                      // 16B chunk id, 8192 total
      *(int4*)&dst[idx * 8] = *(const int4*)&lf[idx * 8];
    }
  } else {
    // f32 row-major direct store: 16-lane groups write 64B contiguous; adjacent
    // n cover 256B/row contiguous -> full-line merging in TCC (r3/r4: no amplification)
    const int r0 = tm * 256 + wr * 128;
    #pragma unroll
    for (int m = 0; m < 8; ++m)
      #pragma unroll
      for (int j = 0; j < 4; ++j) {
        int row = r0 + m * 16 + hi * 4 + j;
        #pragma unroll
        for (int n = 0; n < 4; ++n) {
          int col = c0 + n * 16 + lr;
          if (NCHK && col >= N) continue;
          float v = acc[m][n][j] + bv[n];
          if (ACT == 1) v = fmaxf(v, 0.f);
          if (ACT == 2) v = 1.f / (1.f + __expf(-v));
          Cf[(size_t)row * ldc + col] = v;
        }
      }
  }
}

// =========================================================================
// Fused z = hB @ We3^T + be3 ; scores = z @ emb^T ; argmin ; q gather ; loss
// One block = 128 rows; double-buffered A/W staging with counted vmcnt.
// =========================================================================
__global__ __launch_bounds__(256, 1)
void z_vq(const u16* __restrict__ Atiled,      // hB tiled, K=1024
          const u16* __restrict__ Wrm,         // We3 row-major [64][1024]
          const float* __restrict__ be3,
          const u16* __restrict__ ebf,         // emb bf16 rm64-swizzled [512][64]
          const float* __restrict__ cvec,
          u16* __restrict__ qb,                // out: rm64-swizzled [M][64]
          float* __restrict__ lossacc) {
  __shared__ u16 lsA[2][128 * 64];  // 32 KB
  __shared__ u16 lsW[2][64 * 64];   // 16 KB
  __shared__ u16 embl[512 * 64];    // 64 KB (swizzled rows)
  __shared__ float zls[128 * 68];   // 34.8 KB padded
  __shared__ int bidxl[128];

  const int t = threadIdx.x;
  const int lane = t & 63;
  const int w = t >> 6;
  const int lr = lane & 15, hi = lane >> 4;
  const int tm = blockIdx.x;

  // stage emb (64 KB) up front
  #pragma unroll
  for (int i = 0; i < 16; ++i) {
    const u16* g = ebf + (size_t)((i * 256 + t) << 3);
    u16* l = embl + (size_t)((i * 256 + w * 64) << 3);
    __builtin_amdgcn_global_load_lds((__attribute__((address_space(1))) void*)g,
                                     (__attribute__((address_space(3))) void*)l, 16, 0, 0);
  }

  const size_t abase0 = ((size_t)(tm >> 1) * 16) * 16384 + (size_t)(tm & 1) * 8192;
  auto stageA = [&](int kt, int buf) {
    #pragma unroll
    for (int i = 0; i < 4; ++i) {
      const u16* g = Atiled + abase0 + (size_t)kt * 16384 + ((i * 256 + t) << 3);
      u16* l = lsA[buf] + ((i * 256 + w * 64) << 3);
      __builtin_amdgcn_global_load_lds((__attribute__((address_space(1))) void*)g,
                                       (__attribute__((address_space(3))) void*)l, 16, 0, 0);
    }
  };
  auto stageW = [&](int kt, int buf) {
    #pragma unroll
    for (int i = 0; i < 2; ++i) {
      int c = i * 256 + t;
      int row = c >> 3;
      int cp = (c & 7) ^ (row & 7);
      const u16* g = Wrm + (size_t)row * 1024 + kt * 64 + cp * 8;
      u16* l = lsW[buf] + ((i * 256 + w * 64) << 3);
      __builtin_amdgcn_global_load_lds((__attribute__((address_space(1))) void*)g,
                                       (__attribute__((address_space(3))) void*)l, 16, 0, 0);
    }
  };

  // ---- z GEMM: 128 x 64, K=1024, 2-deep pipelined staging ----
  f32x4 acc[2][4] = {};
  stageA(0, 0); stageW(0, 0);
  stageA(1, 1); stageW(1, 1);
  for (int kt = 0; kt < 16; ++kt) {
    const int bf = kt & 1;
    if (kt < 15) { VM6(); } else { VM0(); }
    __syncthreads();
    #pragma unroll
    for (int kk = 0; kk < 64; kk += 32) {
      bf16x8 af[2], bfr[4];
      #pragma unroll
      for (int m = 0; m < 2; ++m) {
        int row = w * 32 + m * 16 + lr;
        int ch = ((kk >> 3) + hi) ^ (row & 7);
        af[m] = *(const bf16x8*)&lsA[bf][row * 64 + ch * 8];
      }
      #pragma unroll
      for (int n = 0; n < 4; ++n) {
        int row = n * 16 + lr;
        int ch = ((kk >> 3) + hi) ^ (row & 7);
        bfr[n] = *(const bf16x8*)&lsW[bf][row * 64 + ch * 8];
      }
      #pragma unroll
      for (int m = 0; m < 2; ++m)
        #pragma unroll
        for (int n = 0; n < 4; ++n)
          acc[m][n] = __builtin_amdgcn_mfma_f32_16x16x32_bf16(af[m], bfr[n], acc[m][n], 0, 0, 0);
    }
    __syncthreads();
    if (kt + 2 < 16) { stageA(kt + 2, bf); stageW(kt + 2, bf); }
  }

  // ---- z += bias; write to zls (f32, padded) ----
  #pragma unroll
  for (int m = 0; m < 2; ++m)
    #pragma unroll
    for (int j = 0; j < 4; ++j) {
      int row = w * 32 + m * 16 + hi * 4 + j;
      #pragma unroll
      for (int n = 0; n < 4; ++n) {
        int col = n * 16 + lr;
        zls[row * 68 + col] = acc[m][n][j] + be3[col];
      }
    }
  __syncthreads();

  // ---- z bf16 A-fragments from zls ----
  bf16x8 azf[2][2];
  #pragma unroll
  for (int rt = 0; rt < 2; ++rt)
    #pragma unroll
    for (int kf = 0; kf < 2; ++kf) {
      int row = w * 32 + rt * 16 + lr;
      union { bf16x8 v; u16 u[8]; } pk;
      #pragma unroll
      for (int e = 0; e < 8; ++e)
        pk.u[e] = f2bf(zls[row * 68 + kf * 32 + hi * 8 + e]);
      azf[rt][kf] = pk.v;
    }

  // ---- scores + running argmin over 512 codes ----
  float bvv[2][4]; int bii[2][4];
  #pragma unroll
  for (int rt = 0; rt < 2; ++rt)
    #pragma unroll
    for (int j = 0; j < 4; ++j) { bvv[rt][j] = 3.4e38f; bii[rt][j] = 0; }

  for (int ct = 0; ct < 32; ++ct) {
    bf16x8 bqf[2];
    #pragma unroll
    for (int kf = 0; kf < 2; ++kf) {
      int row = ct * 16 + lr;
      int ch = (kf * 4 + hi) ^ (row & 7);
      bqf[kf] = *(const bf16x8*)&embl[row * 64 + ch * 8];
    }
    float cv = cvec[ct * 16 + lr];
    #pragma unroll
    for (int rt = 0; rt < 2; ++rt) {
      f32x4 sc = {};
      sc = __builtin_amdgcn_mfma_f32_16x16x32_bf16(azf[rt][0], bqf[0], sc, 0, 0, 0);
      sc = __builtin_amdgcn_mfma_f32_16x16x32_bf16(azf[rt][1], bqf[1], sc, 0, 0, 0);
      int code = ct * 16 + lr;
      #pragma unroll
      for (int j = 0; j < 4; ++j) {
        float d = cv - sc[j];
        if (d < bvv[rt][j]) { bvv[rt][j] = d; bii[rt][j] = code; }
      }
    }
  }
  #pragma unroll
  for (int off = 1; off < 16; off <<= 1) {
    #pragma unroll
    for (int rt = 0; rt < 2; ++rt)
      #pragma unroll
      for (int j = 0; j < 4; ++j) {
        float ov = __shfl_xor(bvv[rt][j], off);
        int   oi = __shfl_xor(bii[rt][j], off);
        if (ov < bvv[rt][j] || (ov == bvv[rt][j] && oi < bii[rt][j])) {
          bvv[rt][j] = ov; bii[rt][j] = oi;
        }
      }
  }
  if (lr == 0) {
    #pragma unroll
    for (int rt = 0; rt < 2; ++rt)
      #pragma unroll
      for (int j = 0; j < 4; ++j)
        bidxl[w * 32 + rt * 16 + hi * 4 + j] = bii[rt][j];
  }
  __syncthreads();

  // ---- q gather, loss partial, qb write ----
  const int gr0 = tm * 128;
  float ls = 0.f;
  #pragma unroll 4
  for (int r8 = 0; r8 < 32; ++r8) {
    int row = w * 32 + r8;
    int bi = bidxl[row];
    u16 qu = embl[bi * 64 + (((lane >> 3) ^ (bi & 7)) << 3) + (lane & 7)];
    float qf = bf2f(qu);
    float d = qf - zls[row * 68 + lane];
    ls += d * d;
    qb[(size_t)(gr0 + row) * 64 + (((lane >> 3) ^ (row & 7)) << 3) + (lane & 7)] = qu;
  }
  #pragma unroll
  for (int off = 32; off > 0; off >>= 1) ls += __shfl_down(ls, off);
  if (lane == 0) atomicAdd(lossacc, ls);
}

__global__ void loss_final(const float* __restrict__ acc, float* __restrict__ o, float denom) {
  o[0] = acc[0] * 1.25f / denom;
}

// ---------- launch ----------
extern "C" void kernel_launch(void* const* d_in, const int* in_sizes, int n_in,
                              void* d_out, int out_size, void* d_ws, size_t ws_size,
                              hipStream_t stream) {
  const float* x   = (const float*)d_in[0];
  const float* emb = (const float*)d_in[1];
  const float* We1 = (const float*)d_in[2];
  const float* be1 = (const float*)d_in[3];
  const float* We2 = (const float*)d_in[4];
  const float* be2 = (const float*)d_in[5];
  const float* We3 = (const float*)d_in[6];
  const float* be3 = (const float*)d_in[7];
  const float* Wd1 = (const float*)d_in[8];
  const float* bd1 = (const float*)d_in[9];
  const float* Wd2 = (const float*)d_in[10];
  const float* bd2 = (const float*)d_in[11];
  const float* Wd3 = (const float*)d_in[12];
  const float* bd3 = (const float*)d_in[13];

  const int Bn = in_sizes[0] / NIN;              // 32768
  float* out = (float*)d_out;
  float* out_loss = out + (size_t)Bn * NIN;

  char* ws = (char*)d_ws;
  size_t off = 0;
  auto take = [&](size_t bytes) { char* p = ws + off; off += (bytes + 255) & ~(size_t)255; return p; };

  u16*   xpad = (u16*)take((size_t)Bn * NINP * 2);   // tiled
  u16*   hA   = (u16*)take((size_t)Bn * NH * 2);     // tiled: h1 -> h3
  u16*   hB   = (u16*)take((size_t)Bn * NH * 2);     // tiled: h2 -> h4
  u16*   qb   = (u16*)take((size_t)Bn * ND * 2);     // rm64-swizzled (== tiled, Cp=64)
  u16*   we1p = (u16*)take((size_t)NH * NINP * 2);   // tiled
  u16*   we2b = (u16*)take((size_t)NH * NH * 2);     // tiled
  u16*   we3r = (u16*)take((size_t)64 * NH * 2);     // row-major [64][1024]
  u16*   wd1b = (u16*)take((size_t)NH * ND * 2);     // rm64-swizzled (== tiled, Cp=64)
  u16*   wd2b = (u16*)take((size_t)NH * NH * 2);     // tiled
  u16*   wd3p = (u16*)take((size_t)NOUTP * NH * 2);  // tiled, rows 784..1023 zero
  u16*   embb = (u16*)take((size_t)NE * ND * 2);     // rm64-swizzled
  float* cvec = (float*)take(NE * 4);
  float* lossa = (float*)take(4);

  hipMemsetAsync(lossa, 0, 4, stream);

  cast_tiled4<<<dim3(1, Bn),    256, 0, stream>>>(x,   xpad, Bn,  NIN, NINP);
  cast_tiled4<<<dim3(1, NH),    256, 0, stream>>>(We1, we1p, NH,  NIN, NINP);
  cast_tiled4<<<dim3(1, NH),    256, 0, stream>>>(We2, we2b, NH,  NH,  NH);
  cast_rm4  <<<dim3(1, 64),     256, 0, stream>>>(We3, we3r, 64,  NH,  NH);
  cast_rm64swz<<<NH, 64, 0, stream>>>(Wd1, wd1b, NH);
  cast_tiled4<<<dim3(1, NH),    256, 0, stream>>>(Wd2, wd2b, NH,  NH,  NH);
  cast_tiled4<<<dim3(1, NOUTP), 256, 0, stream>>>(Wd3, wd3p, NIN, NH,  NH);
  emb_prep<<<NE, 64, 0, stream>>>(emb, embb, cvec);

  // encoder
  gemm256<1,1,false><<<512, 512, 0, stream>>>(xpad, we1p, be1, nullptr, hA, Bn, NH, NINP, NH, 4);
  gemm256<1,1,false><<<512, 512, 0, stream>>>(hA, we2b, be2, nullptr, hB, Bn, NH, NH, NH, 4);
  // fused z + VQ
  z_vq<<<Bn / 128, 256, 0, stream>>>(hB, we3r, be3, embb, cvec, qb, lossa);
  // decoder
  gemm256<1,1,false><<<512, 512, 0, stream>>>(qb, wd1b, bd1, nullptr, hA, Bn, NH, 64, NH, 4);
  gemm256<1,1,false><<<512, 512, 0, stream>>>(hA, wd2b, bd2, nullptr, hB, Bn, NH, NH, NH, 4);
  gemm256<2,0,true ><<<512, 512, 0, stream>>>(hB, wd3p, bd3, out, nullptr, Bn, NIN, NH, NIN, 4);

  loss_final<<<1, 1, 0, stream>>>(lossa, out_loss, (float)Bn * ND);
}